// Round 1
// baseline (755.418 us; speedup 1.0000x reference)
//
#include <hip/hip_runtime.h>
#include <math.h>

#define EPSV 1e-5f

__device__ __forceinline__ float gelu_f(float x) {
    return 0.5f * x * (1.0f + erff(x * 0.70710678118654752440f));
}

// ---------------- degree / dinv ----------------
__global__ void deg_kernel(const int* __restrict__ ei, int* __restrict__ deg, int E) {
    int stride = gridDim.x * blockDim.x;
    for (int e = blockIdx.x * blockDim.x + threadIdx.x; e < E; e += stride)
        atomicAdd(&deg[ei[E + e]], 1);   // dst occurrences
}

__global__ void dinv_kernel(const int* __restrict__ deg, float* __restrict__ dinv, int N) {
    int i = blockIdx.x * blockDim.x + threadIdx.x;
    if (i < N) dinv[i] = rsqrtf((float)(deg[i] + 1));  // +1 self loop
}

// ---------------- GEMM: C[i][c] = (sum_k A[i][k] W[k][c]) * dinv[i] ----------------
// 64x64 tile, BK=16, 256 threads, 4x4 micro-tile per thread.
__global__ __launch_bounds__(256) void gemm_scale_kernel(
    const float* __restrict__ A, const float* __restrict__ W,
    const float* __restrict__ dinv, float* __restrict__ C,
    int M, int K, int Nc)
{
    __shared__ float As[64][17];
    __shared__ float4 Ws4[16][16];
    const int tid = threadIdx.x;
    const int tx = tid & 15, ty = tid >> 4;
    const int row0 = blockIdx.y * 64, col0 = blockIdx.x * 64;
    float acc[4][4] = {};
    const int ar = tid >> 2, ac4 = (tid & 3) * 4;   // A-tile coords
    const int wr = tid >> 4, wc4 = (tid & 15) * 4;  // W-tile coords

    for (int kk = 0; kk < K; kk += 16) {
        float4 av = make_float4(0.f, 0.f, 0.f, 0.f);
        int grow = row0 + ar;
        if (grow < M) av = *(const float4*)(A + (long)grow * K + kk + ac4);
        As[ar][ac4 + 0] = av.x; As[ar][ac4 + 1] = av.y;
        As[ar][ac4 + 2] = av.z; As[ar][ac4 + 3] = av.w;
        Ws4[wr][tid & 15] = *(const float4*)(W + (long)(kk + wr) * Nc + col0 + wc4);
        __syncthreads();
#pragma unroll
        for (int k = 0; k < 16; ++k) {
            float4 b4 = Ws4[k][tx];
            float a0 = As[ty * 4 + 0][k];
            float a1 = As[ty * 4 + 1][k];
            float a2 = As[ty * 4 + 2][k];
            float a3 = As[ty * 4 + 3][k];
            acc[0][0] = fmaf(a0, b4.x, acc[0][0]); acc[0][1] = fmaf(a0, b4.y, acc[0][1]);
            acc[0][2] = fmaf(a0, b4.z, acc[0][2]); acc[0][3] = fmaf(a0, b4.w, acc[0][3]);
            acc[1][0] = fmaf(a1, b4.x, acc[1][0]); acc[1][1] = fmaf(a1, b4.y, acc[1][1]);
            acc[1][2] = fmaf(a1, b4.z, acc[1][2]); acc[1][3] = fmaf(a1, b4.w, acc[1][3]);
            acc[2][0] = fmaf(a2, b4.x, acc[2][0]); acc[2][1] = fmaf(a2, b4.y, acc[2][1]);
            acc[2][2] = fmaf(a2, b4.z, acc[2][2]); acc[2][3] = fmaf(a2, b4.w, acc[2][3]);
            acc[3][0] = fmaf(a3, b4.x, acc[3][0]); acc[3][1] = fmaf(a3, b4.y, acc[3][1]);
            acc[3][2] = fmaf(a3, b4.z, acc[3][2]); acc[3][3] = fmaf(a3, b4.w, acc[3][3]);
        }
        __syncthreads();
    }
#pragma unroll
    for (int i = 0; i < 4; ++i) {
        int grow = row0 + ty * 4 + i;
        if (grow < M) {
            float dv = dinv[grow];
            float4 o = make_float4(acc[i][0] * dv, acc[i][1] * dv, acc[i][2] * dv, acc[i][3] * dv);
            *(float4*)(C + (long)grow * Nc + col0 + tx * 4) = o;
        }
    }
}

// ---------------- edge scatter: agg[dst] += hs[src] ----------------
__global__ __launch_bounds__(256) void scatter_kernel(
    const float* __restrict__ hs, const int* __restrict__ ei,
    float* __restrict__ agg, int E, int log2f, long total)
{
    long stride = (long)gridDim.x * blockDim.x;
    int fmask = (1 << log2f) - 1;
    for (long idx = (long)blockIdx.x * blockDim.x + threadIdx.x; idx < total; idx += stride) {
        int e = (int)(idx >> log2f);
        int c = (int)idx & fmask;
        int s = ei[e];
        int d = ei[E + e];
        atomicAdd(agg + (((long)d << log2f) + c), hs[((long)s << log2f) + c]);
    }
}

// ---------------- finalize: t = dinv[i]*(agg+hs)+b  (t may alias agg) ----------------
__global__ __launch_bounds__(256) void finalize_kernel(
    const float* agg, const float* __restrict__ hs,
    const float* __restrict__ dinv, const float* __restrict__ bias,
    float* t, int log2f, long total)
{
    long stride = (long)gridDim.x * blockDim.x;
    int fmask = (1 << log2f) - 1;
    for (long idx = (long)blockIdx.x * blockDim.x + threadIdx.x; idx < total; idx += stride) {
        int i = (int)(idx >> log2f);
        int c = (int)idx & fmask;
        t[idx] = dinv[i] * (agg[idx] + hs[idx]) + bias[c];
    }
}

// ---------------- per-column sum / sum^2 ----------------
__global__ __launch_bounds__(256) void colstats_kernel(
    const float* __restrict__ t, float* __restrict__ s1g, float* __restrict__ s2g,
    int M, int log2f, int rowsPerBlock)
{
    int fout = 1 << log2f;
    int c = threadIdx.x & (fout - 1);
    int rl = threadIdx.x >> log2f;
    int cpt = 256 >> log2f;
    int r0 = blockIdx.x * rowsPerBlock;
    int rend = r0 + rowsPerBlock; if (rend > M) rend = M;
    float a1 = 0.f, a2 = 0.f;
    for (int r = r0 + rl; r < rend; r += cpt) {
        float v = t[((long)r << log2f) + c];
        a1 += v; a2 += v * v;
    }
    __shared__ float sh1[256], sh2[256];
    sh1[threadIdx.x] = a1; sh2[threadIdx.x] = a2;
    __syncthreads();
    if (threadIdx.x < fout) {
        for (int j = 1; j < cpt; ++j) { a1 += sh1[c + j * fout]; a2 += sh2[c + j * fout]; }
        atomicAdd(&s1g[c], a1);
        atomicAdd(&s2g[c], a2);
    }
}

// ---------------- mean / istd per column ----------------
__global__ void statfinal_kernel(const float* __restrict__ s1, const float* __restrict__ s2,
                                 const float* __restrict__ ga,
                                 float* __restrict__ meanv, float* __restrict__ istdv,
                                 int M, int fout)
{
    int c = threadIdx.x;
    if (c < fout) {
        float m = s1[c] / (float)M;
        float a = ga[c];
        float var = s2[c] / (float)M - 2.f * a * m * m + a * a * m * m;
        meanv[c] = m;
        istdv[c] = rsqrtf(var + EPSV);
    }
}

// ---------------- graphnorm + gelu (+ residual) ----------------
__global__ __launch_bounds__(256) void normgelu_kernel(
    const float* __restrict__ t, const float* __restrict__ meanv,
    const float* __restrict__ istdv, const float* __restrict__ gw,
    const float* __restrict__ gb, const float* __restrict__ ga,
    const float* __restrict__ res, float* __restrict__ out,
    int log2f, long total)
{
    long stride = (long)gridDim.x * blockDim.x;
    int fmask = (1 << log2f) - 1;
    for (long idx = (long)blockIdx.x * blockDim.x + threadIdx.x; idx < total; idx += stride) {
        int c = (int)idx & fmask;
        float v = t[idx];
        float y = gw[c] * (v - ga[c] * meanv[c]) * istdv[c] + gb[c];
        y = gelu_f(y);
        if (res) y += res[idx];
        out[idx] = y;
    }
}

// ---------------- pooling (fout = 64) ----------------
__device__ __forceinline__ void atomicMaxFloat(float* addr, float val) {
    unsigned* ua = (unsigned*)addr;
    unsigned old = *ua;
    while (true) {
        float of = __uint_as_float(old);
        if (of >= val) break;
        unsigned assumed = old;
        old = atomicCAS(ua, assumed, __float_as_uint(val));
        if (old == assumed) break;
    }
}

__global__ void initpool_kernel(float* __restrict__ psum, float* __restrict__ pmax) {
    int t = threadIdx.x;
    psum[t] = 0.f;
    pmax[t] = -INFINITY;
}

__global__ __launch_bounds__(256) void colpool_kernel(
    const float* __restrict__ x, float* __restrict__ psum, float* __restrict__ pmax,
    int M, int rowsPerBlock)
{
    int c = threadIdx.x & 63;
    int rl = threadIdx.x >> 6;
    int r0 = blockIdx.x * rowsPerBlock;
    int rend = r0 + rowsPerBlock; if (rend > M) rend = M;
    float a1 = 0.f, am = -INFINITY;
    for (int r = r0 + rl; r < rend; r += 4) {
        float v = x[(long)r * 64 + c];
        a1 += v; am = fmaxf(am, v);
    }
    __shared__ float sh1[256], shm[256];
    sh1[threadIdx.x] = a1; shm[threadIdx.x] = am;
    __syncthreads();
    if (threadIdx.x < 64) {
        for (int j = 1; j < 4; ++j) {
            a1 += sh1[c + j * 64];
            am = fmaxf(am, shm[c + j * 64]);
        }
        atomicAdd(&psum[c], a1);
        atomicMaxFloat(&pmax[c], am);
    }
}

// ---------------- head: pooled -> linear -> layernorm -> gelu -> linear ----------------
__global__ void head_kernel(const float* __restrict__ psum, const float* __restrict__ pmax,
                            const float* __restrict__ wc1, const float* __restrict__ bc1,
                            const float* __restrict__ lnw, const float* __restrict__ lnb,
                            const float* __restrict__ wc2, const float* __restrict__ bc2,
                            float* __restrict__ out, int M)
{
    __shared__ float p[192];
    int t = threadIdx.x; // 64 threads = 1 wave
    float s = psum[t];
    p[t] = s / (float)M;
    p[64 + t] = pmax[t];
    p[128 + t] = s;
    __syncthreads();
    float h = bc1[t];
    for (int k = 0; k < 192; ++k) h = fmaf(p[k], wc1[k * 64 + t], h);
    float m = h;
    for (int off = 32; off > 0; off >>= 1) m += __shfl_xor(m, off);
    m *= (1.f / 64.f);
    float d = h - m;
    float v = d * d;
    for (int off = 32; off > 0; off >>= 1) v += __shfl_xor(v, off);
    v *= (1.f / 64.f);
    float y = d * rsqrtf(v + EPSV) * lnw[t] + lnb[t];
    y = gelu_f(y);
    float o0 = y * wc2[t * 2 + 0];
    float o1 = y * wc2[t * 2 + 1];
    for (int off = 32; off > 0; off >>= 1) {
        o0 += __shfl_xor(o0, off);
        o1 += __shfl_xor(o1, off);
    }
    if (t == 0) {
        out[0] = o0 + bc2[0];
        out[1] = o1 + bc2[1];
    }
}

extern "C" void kernel_launch(void* const* d_in, const int* in_sizes, int n_in,
                              void* d_out, int out_size, void* d_ws, size_t ws_size,
                              hipStream_t stream)
{
    const float* x    = (const float*)d_in[0];
    const int*   ei   = (const int*)d_in[1];
    const float* w0   = (const float*)d_in[2];
    const float* b0   = (const float*)d_in[3];
    const float* gn0w = (const float*)d_in[4];
    const float* gn0b = (const float*)d_in[5];
    const float* gn0a = (const float*)d_in[6];
    const float* w1   = (const float*)d_in[7];
    const float* b1   = (const float*)d_in[8];
    const float* gn1w = (const float*)d_in[9];
    const float* gn1b = (const float*)d_in[10];
    const float* gn1a = (const float*)d_in[11];
    const float* w2   = (const float*)d_in[12];
    const float* b2   = (const float*)d_in[13];
    const float* gn2w = (const float*)d_in[14];
    const float* gn2b = (const float*)d_in[15];
    const float* gn2a = (const float*)d_in[16];
    const float* wc1  = (const float*)d_in[17];
    const float* bc1  = (const float*)d_in[18];
    const float* lnw  = (const float*)d_in[19];
    const float* lnb  = (const float*)d_in[20];
    const float* wc2  = (const float*)d_in[21];
    const float* bc2  = (const float*)d_in[22];

    const int N = in_sizes[0] / 256;
    const int E = in_sizes[1] / 2;

    float* ws = (float*)d_ws;
    const size_t BIG = (size_t)N * 256;
    float* BUF0  = ws;
    float* BUF1  = ws + BIG;
    float* dinv  = ws + 2 * BIG;
    int*   deg   = (int*)(ws + 2 * BIG + N);
    float* cs1   = ws + 2 * BIG + 2 * N;   // 256
    float* cs2   = cs1 + 256;
    float* meanv = cs2 + 256;
    float* istdv = meanv + 256;
    float* psum  = istdv + 256;            // 64
    float* pmax  = psum + 64;

    // degrees -> dinv
    hipMemsetAsync(deg, 0, (size_t)N * sizeof(int), stream);
    deg_kernel<<<1024, 256, 0, stream>>>(ei, deg, E);
    dinv_kernel<<<(N + 255) / 256, 256, 0, stream>>>(deg, dinv, N);

    struct Layer {
        const float *w, *b, *gw, *gb, *ga;
        int K, F, lf;
    } L[3] = {
        { w0, b0, gn0w, gn0b, gn0a, 256, 256, 8 },
        { w1, b1, gn1w, gn1b, gn1a, 256, 128, 7 },
        { w2, b2, gn2w, gn2b, gn2a, 128,  64, 6 },
    };
    // buffer schedule (2 big ping-pong buffers):
    // L0: cur=x    hs=BUF0 agg/t=BUF1 out=BUF1 res=x
    // L1: cur=BUF1 hs=BUF0 agg/t=BUF1 out=BUF0
    // L2: cur=BUF0 hs=BUF1 agg/t=BUF0 out=BUF0
    float*       hsb[3]  = { BUF0, BUF0, BUF1 };
    float*       aggb[3] = { BUF1, BUF1, BUF0 };
    float*       outb[3] = { BUF1, BUF0, BUF0 };
    const float* resb[3] = { x, nullptr, nullptr };

    const float* cur = x;
    for (int li = 0; li < 3; ++li) {
        const int K = L[li].K, F = L[li].F, lf = L[li].lf;
        const long total = (long)N << lf;
        dim3 gg(F / 64, (N + 63) / 64);
        gemm_scale_kernel<<<gg, 256, 0, stream>>>(cur, L[li].w, dinv, hsb[li], N, K, F);
        hipMemsetAsync(aggb[li], 0, (size_t)total * sizeof(float), stream);
        long etotal = (long)E << lf;
        long sb = (etotal + 255) / 256; if (sb > 8192) sb = 8192;
        scatter_kernel<<<(int)sb, 256, 0, stream>>>(hsb[li], ei, aggb[li], E, lf, etotal);
        long fb = (total + 255) / 256; if (fb > 4096) fb = 4096;
        finalize_kernel<<<(int)fb, 256, 0, stream>>>(aggb[li], hsb[li], dinv, L[li].b, aggb[li], lf, total);
        hipMemsetAsync(cs1, 0, 2 * 256 * sizeof(float), stream);
        colstats_kernel<<<(N + 127) / 128, 256, 0, stream>>>(aggb[li], cs1, cs2, N, lf, 128);
        statfinal_kernel<<<1, F, 0, stream>>>(cs1, cs2, L[li].ga, meanv, istdv, N, F);
        normgelu_kernel<<<(int)fb, 256, 0, stream>>>(aggb[li], meanv, istdv,
                                                     L[li].gw, L[li].gb, L[li].ga,
                                                     resb[li], outb[li], lf, total);
        cur = outb[li];
    }

    // pooling + head
    initpool_kernel<<<1, 64, 0, stream>>>(psum, pmax);
    colpool_kernel<<<(N + 127) / 128, 256, 0, stream>>>(cur, psum, pmax, N, 128);
    head_kernel<<<1, 64, 0, stream>>>(psum, pmax, wc1, bc1, lnw, lnb, wc2, bc2,
                                      (float*)d_out, N);
}

// Round 2
// 692.332 us; speedup vs baseline: 1.0911x; 1.0911x over previous
//
#include <hip/hip_runtime.h>
#include <math.h>

#define EPSV 1e-5f

__device__ __forceinline__ float gelu_f(float x) {
    return 0.5f * x * (1.0f + erff(x * 0.70710678118654752440f));
}

// ---------------- degree / dinv ----------------
__global__ void deg_kernel(const int* __restrict__ ei, int* __restrict__ deg, int E) {
    int stride = gridDim.x * blockDim.x;
    for (int e = blockIdx.x * blockDim.x + threadIdx.x; e < E; e += stride)
        atomicAdd(&deg[ei[E + e]], 1);   // dst occurrences
}

__global__ void dinv_kernel(const int* __restrict__ deg, float* __restrict__ dinv, int N) {
    int i = blockIdx.x * blockDim.x + threadIdx.x;
    if (i < N) dinv[i] = rsqrtf((float)(deg[i] + 1));  // +1 self loop
}

// ---------------- exclusive scan of deg -> off  (single block, 1024 threads) ----------------
__global__ __launch_bounds__(1024) void scan_kernel(const int* __restrict__ deg,
                                                    int* __restrict__ off, int N) {
    __shared__ int sh[1024];
    int t = threadIdx.x;
    int chunk = (N + 1023) >> 10;
    int b = t * chunk;
    int e = b + chunk; if (e > N) e = N;
    int s = 0;
    for (int i = b; i < e; ++i) s += deg[i];
    sh[t] = s;
    __syncthreads();
    for (int d = 1; d < 1024; d <<= 1) {
        int v = (t >= d) ? sh[t - d] : 0;
        __syncthreads();
        sh[t] += v;
        __syncthreads();
    }
    int run = (t > 0) ? sh[t - 1] : 0;
    for (int i = b; i < e; ++i) { off[i] = run; run += deg[i]; }
    if (t == 1023) off[N] = sh[1023];
}

// ---------------- CSR fill: csr[off[d] + rank] = src ----------------
__global__ void fill_kernel(const int* __restrict__ ei, const int* __restrict__ off,
                            int* __restrict__ fill, int* __restrict__ csr, int E) {
    int stride = gridDim.x * blockDim.x;
    for (int e = blockIdx.x * blockDim.x + threadIdx.x; e < E; e += stride) {
        int d = ei[E + e];
        int p = off[d] + atomicAdd(&fill[d], 1);
        csr[p] = ei[e];
    }
}

// ---------------- GEMM: C[i][c] = (sum_k A[i][k] W[k][c]) * dinv[i] ----------------
// 64x64 tile, BK=16, 256 threads, 4x4 micro-tile per thread.
__global__ __launch_bounds__(256) void gemm_scale_kernel(
    const float* __restrict__ A, const float* __restrict__ W,
    const float* __restrict__ dinv, float* __restrict__ C,
    int M, int K, int Nc)
{
    __shared__ float As[64][17];
    __shared__ float4 Ws4[16][16];
    const int tid = threadIdx.x;
    const int tx = tid & 15, ty = tid >> 4;
    const int row0 = blockIdx.y * 64, col0 = blockIdx.x * 64;
    float acc[4][4] = {};
    const int ar = tid >> 2, ac4 = (tid & 3) * 4;   // A-tile coords
    const int wr = tid >> 4, wc4 = (tid & 15) * 4;  // W-tile coords

    for (int kk = 0; kk < K; kk += 16) {
        float4 av = make_float4(0.f, 0.f, 0.f, 0.f);
        int grow = row0 + ar;
        if (grow < M) av = *(const float4*)(A + (long)grow * K + kk + ac4);
        As[ar][ac4 + 0] = av.x; As[ar][ac4 + 1] = av.y;
        As[ar][ac4 + 2] = av.z; As[ar][ac4 + 3] = av.w;
        Ws4[wr][tid & 15] = *(const float4*)(W + (long)(kk + wr) * Nc + col0 + wc4);
        __syncthreads();
#pragma unroll
        for (int k = 0; k < 16; ++k) {
            float4 b4 = Ws4[k][tx];
            float a0 = As[ty * 4 + 0][k];
            float a1 = As[ty * 4 + 1][k];
            float a2 = As[ty * 4 + 2][k];
            float a3 = As[ty * 4 + 3][k];
            acc[0][0] = fmaf(a0, b4.x, acc[0][0]); acc[0][1] = fmaf(a0, b4.y, acc[0][1]);
            acc[0][2] = fmaf(a0, b4.z, acc[0][2]); acc[0][3] = fmaf(a0, b4.w, acc[0][3]);
            acc[1][0] = fmaf(a1, b4.x, acc[1][0]); acc[1][1] = fmaf(a1, b4.y, acc[1][1]);
            acc[1][2] = fmaf(a1, b4.z, acc[1][2]); acc[1][3] = fmaf(a1, b4.w, acc[1][3]);
            acc[2][0] = fmaf(a2, b4.x, acc[2][0]); acc[2][1] = fmaf(a2, b4.y, acc[2][1]);
            acc[2][2] = fmaf(a2, b4.z, acc[2][2]); acc[2][3] = fmaf(a2, b4.w, acc[2][3]);
            acc[3][0] = fmaf(a3, b4.x, acc[3][0]); acc[3][1] = fmaf(a3, b4.y, acc[3][1]);
            acc[3][2] = fmaf(a3, b4.z, acc[3][2]); acc[3][3] = fmaf(a3, b4.w, acc[3][3]);
        }
        __syncthreads();
    }
#pragma unroll
    for (int i = 0; i < 4; ++i) {
        int grow = row0 + ty * 4 + i;
        if (grow < M) {
            float dv = dinv[grow];
            float4 o = make_float4(acc[i][0] * dv, acc[i][1] * dv, acc[i][2] * dv, acc[i][3] * dv);
            *(float4*)(C + (long)grow * Nc + col0 + tx * 4) = o;
        }
    }
}

// ---------------- gather: t[d] = dinv[d]*(hs[d] + sum_{s in CSR[d]} hs[s]) + b
//                  fused with per-column sum / sumsq partials ----------------
template<int F>
__global__ __launch_bounds__(256) void gather_kernel(
    const float* __restrict__ hs, const int* __restrict__ off,
    const int* __restrict__ csr, const float* __restrict__ dinv,
    const float* __restrict__ bias, float* __restrict__ t,
    float* __restrict__ cs1, float* __restrict__ cs2, int N)
{
    constexpr int LPN = F / 4;        // float4 lanes per node row
    constexpr int NPB = 256 / LPN;    // node slots per block
    const int lane = threadIdx.x % LPN;
    const int slot = threadIdx.x / LPN;
    const float4* hs4 = (const float4*)hs;
    float4* t4 = (float4*)t;
    const float4 bv = ((const float4*)bias)[lane];

    float4 a1 = make_float4(0.f, 0.f, 0.f, 0.f);
    float4 a2 = make_float4(0.f, 0.f, 0.f, 0.f);

    for (int d = blockIdx.x * NPB + slot; d < N; d += gridDim.x * NPB) {
        float4 acc = hs4[(long)d * LPN + lane];   // self loop
        const int e0 = off[d], e1 = off[d + 1];
        for (int e = e0; e < e1; ++e) {
            int s = csr[e];
            float4 v = hs4[(long)s * LPN + lane];
            acc.x += v.x; acc.y += v.y; acc.z += v.z; acc.w += v.w;
        }
        float dv = dinv[d];
        float4 o;
        o.x = fmaf(dv, acc.x, bv.x);
        o.y = fmaf(dv, acc.y, bv.y);
        o.z = fmaf(dv, acc.z, bv.z);
        o.w = fmaf(dv, acc.w, bv.w);
        t4[(long)d * LPN + lane] = o;
        a1.x += o.x; a1.y += o.y; a1.z += o.z; a1.w += o.w;
        a2.x += o.x * o.x; a2.y += o.y * o.y; a2.z += o.z * o.z; a2.w += o.w * o.w;
    }

    // reduce stats across node slots (same feature lane), then one atomic set per block
    __shared__ float red[8][256];
    red[0][threadIdx.x] = a1.x; red[1][threadIdx.x] = a1.y;
    red[2][threadIdx.x] = a1.z; red[3][threadIdx.x] = a1.w;
    red[4][threadIdx.x] = a2.x; red[5][threadIdx.x] = a2.y;
    red[6][threadIdx.x] = a2.z; red[7][threadIdx.x] = a2.w;
    __syncthreads();
    if (slot == 0) {
#pragma unroll
        for (int k = 0; k < 8; ++k) {
            float s = 0.f;
            for (int j = 0; j < NPB; ++j) s += red[k][j * LPN + lane];
            if (k < 4) atomicAdd(&cs1[lane * 4 + k], s);
            else       atomicAdd(&cs2[lane * 4 + (k - 4)], s);
        }
    }
}

// ---------------- mean / istd per column ----------------
__global__ void statfinal_kernel(const float* __restrict__ s1, const float* __restrict__ s2,
                                 const float* __restrict__ ga,
                                 float* __restrict__ meanv, float* __restrict__ istdv,
                                 int M, int fout)
{
    int c = threadIdx.x;
    if (c < fout) {
        float m = s1[c] / (float)M;
        float a = ga[c];
        float var = s2[c] / (float)M - 2.f * a * m * m + a * a * m * m;
        meanv[c] = m;
        istdv[c] = rsqrtf(var + EPSV);
    }
}

// ---------------- graphnorm + gelu (+ residual) ----------------
__global__ __launch_bounds__(256) void normgelu_kernel(
    const float* __restrict__ t, const float* __restrict__ meanv,
    const float* __restrict__ istdv, const float* __restrict__ gw,
    const float* __restrict__ gb, const float* __restrict__ ga,
    const float* __restrict__ res, float* __restrict__ out,
    int log2f, long total)
{
    long stride = (long)gridDim.x * blockDim.x;
    int fmask = (1 << log2f) - 1;
    for (long idx = (long)blockIdx.x * blockDim.x + threadIdx.x; idx < total; idx += stride) {
        int c = (int)idx & fmask;
        float v = t[idx];
        float y = gw[c] * (v - ga[c] * meanv[c]) * istdv[c] + gb[c];
        y = gelu_f(y);
        if (res) y += res[idx];
        out[idx] = y;
    }
}

// ---------------- pooling (fout = 64) ----------------
__device__ __forceinline__ void atomicMaxFloat(float* addr, float val) {
    unsigned* ua = (unsigned*)addr;
    unsigned old = *ua;
    while (true) {
        float of = __uint_as_float(old);
        if (of >= val) break;
        unsigned assumed = old;
        old = atomicCAS(ua, assumed, __float_as_uint(val));
        if (old == assumed) break;
    }
}

__global__ void initpool_kernel(float* __restrict__ psum, float* __restrict__ pmax) {
    int t = threadIdx.x;
    psum[t] = 0.f;
    pmax[t] = -INFINITY;
}

__global__ __launch_bounds__(256) void colpool_kernel(
    const float* __restrict__ x, float* __restrict__ psum, float* __restrict__ pmax,
    int M, int rowsPerBlock)
{
    int c = threadIdx.x & 63;
    int rl = threadIdx.x >> 6;
    int r0 = blockIdx.x * rowsPerBlock;
    int rend = r0 + rowsPerBlock; if (rend > M) rend = M;
    float a1 = 0.f, am = -INFINITY;
    for (int r = r0 + rl; r < rend; r += 4) {
        float v = x[(long)r * 64 + c];
        a1 += v; am = fmaxf(am, v);
    }
    __shared__ float sh1[256], shm[256];
    sh1[threadIdx.x] = a1; shm[threadIdx.x] = am;
    __syncthreads();
    if (threadIdx.x < 64) {
        for (int j = 1; j < 4; ++j) {
            a1 += sh1[c + j * 64];
            am = fmaxf(am, shm[c + j * 64]);
        }
        atomicAdd(&psum[c], a1);
        atomicMaxFloat(&pmax[c], am);
    }
}

// ---------------- head: pooled -> linear -> layernorm -> gelu -> linear ----------------
__global__ void head_kernel(const float* __restrict__ psum, const float* __restrict__ pmax,
                            const float* __restrict__ wc1, const float* __restrict__ bc1,
                            const float* __restrict__ lnw, const float* __restrict__ lnb,
                            const float* __restrict__ wc2, const float* __restrict__ bc2,
                            float* __restrict__ out, int M)
{
    __shared__ float p[192];
    int t = threadIdx.x; // 64 threads = 1 wave
    float s = psum[t];
    p[t] = s / (float)M;
    p[64 + t] = pmax[t];
    p[128 + t] = s;
    __syncthreads();
    float h = bc1[t];
    for (int k = 0; k < 192; ++k) h = fmaf(p[k], wc1[k * 64 + t], h);
    float m = h;
    for (int off = 32; off > 0; off >>= 1) m += __shfl_xor(m, off);
    m *= (1.f / 64.f);
    float d = h - m;
    float v = d * d;
    for (int off = 32; off > 0; off >>= 1) v += __shfl_xor(v, off);
    v *= (1.f / 64.f);
    float y = d * rsqrtf(v + EPSV) * lnw[t] + lnb[t];
    y = gelu_f(y);
    float o0 = y * wc2[t * 2 + 0];
    float o1 = y * wc2[t * 2 + 1];
    for (int off = 32; off > 0; off >>= 1) {
        o0 += __shfl_xor(o0, off);
        o1 += __shfl_xor(o1, off);
    }
    if (t == 0) {
        out[0] = o0 + bc2[0];
        out[1] = o1 + bc2[1];
    }
}

extern "C" void kernel_launch(void* const* d_in, const int* in_sizes, int n_in,
                              void* d_out, int out_size, void* d_ws, size_t ws_size,
                              hipStream_t stream)
{
    const float* x    = (const float*)d_in[0];
    const int*   ei   = (const int*)d_in[1];
    const float* w0   = (const float*)d_in[2];
    const float* b0   = (const float*)d_in[3];
    const float* gn0w = (const float*)d_in[4];
    const float* gn0b = (const float*)d_in[5];
    const float* gn0a = (const float*)d_in[6];
    const float* w1   = (const float*)d_in[7];
    const float* b1   = (const float*)d_in[8];
    const float* gn1w = (const float*)d_in[9];
    const float* gn1b = (const float*)d_in[10];
    const float* gn1a = (const float*)d_in[11];
    const float* w2   = (const float*)d_in[12];
    const float* b2   = (const float*)d_in[13];
    const float* gn2w = (const float*)d_in[14];
    const float* gn2b = (const float*)d_in[15];
    const float* gn2a = (const float*)d_in[16];
    const float* wc1  = (const float*)d_in[17];
    const float* bc1  = (const float*)d_in[18];
    const float* lnw  = (const float*)d_in[19];
    const float* lnb  = (const float*)d_in[20];
    const float* wc2  = (const float*)d_in[21];
    const float* bc2  = (const float*)d_in[22];

    const int N = in_sizes[0] / 256;
    const int E = in_sizes[1] / 2;

    float* ws = (float*)d_ws;
    const size_t BIG = (size_t)N * 256;
    float* BUF0  = ws;                      // hs
    float* BUF1  = ws + BIG;                // t / activations
    float* dinv  = ws + 2 * BIG;            // N floats
    int*   deg   = (int*)(dinv + N);        // N ints
    int*   off   = deg + N;                 // N+1 ints
    int*   fill  = off + N + 1;             // N ints
    int*   csr   = fill + N;                // E ints
    float* cs1   = (float*)(csr + E);       // 256
    float* cs2   = cs1 + 256;
    float* meanv = cs2 + 256;
    float* istdv = meanv + 256;
    float* psum  = istdv + 256;             // 64
    float* pmax  = psum + 64;

    // degrees -> dinv, CSR build
    hipMemsetAsync(deg, 0, (size_t)N * sizeof(int), stream);
    hipMemsetAsync(fill, 0, (size_t)N * sizeof(int), stream);
    deg_kernel<<<1024, 256, 0, stream>>>(ei, deg, E);
    dinv_kernel<<<(N + 255) / 256, 256, 0, stream>>>(deg, dinv, N);
    scan_kernel<<<1, 1024, 0, stream>>>(deg, off, N);
    fill_kernel<<<1024, 256, 0, stream>>>(ei, off, fill, csr, E);

    struct Layer {
        const float *w, *b, *gw, *gb, *ga;
        int K, F, lf;
    } L[3] = {
        { w0, b0, gn0w, gn0b, gn0a, 256, 256, 8 },
        { w1, b1, gn1w, gn1b, gn1a, 256, 128, 7 },
        { w2, b2, gn2w, gn2b, gn2a, 128,  64, 6 },
    };
    const float* resb[3] = { x, nullptr, nullptr };

    // Every layer: GEMM cur->BUF0 (hs), gather BUF0->BUF1 (t), normgelu in-place BUF1.
    const float* cur = x;
    for (int li = 0; li < 3; ++li) {
        const int K = L[li].K, F = L[li].F, lf = L[li].lf;
        const long total = (long)N << lf;
        dim3 gg(F / 64, (N + 63) / 64);
        gemm_scale_kernel<<<gg, 256, 0, stream>>>(cur, L[li].w, dinv, BUF0, N, K, F);

        hipMemsetAsync(cs1, 0, 2 * 256 * sizeof(float), stream);
        if (F == 256) {
            int npb = 4, groups = (N + npb - 1) / npb;
            int blocks = groups < 1280 ? groups : 1280;
            gather_kernel<256><<<blocks, 256, 0, stream>>>(BUF0, off, csr, dinv, L[li].b, BUF1, cs1, cs2, N);
        } else if (F == 128) {
            int npb = 8, groups = (N + npb - 1) / npb;
            int blocks = groups < 1280 ? groups : 1280;
            gather_kernel<128><<<blocks, 256, 0, stream>>>(BUF0, off, csr, dinv, L[li].b, BUF1, cs1, cs2, N);
        } else {
            int npb = 16, groups = (N + npb - 1) / npb;
            int blocks = groups < 1280 ? groups : 1280;
            gather_kernel<64><<<blocks, 256, 0, stream>>>(BUF0, off, csr, dinv, L[li].b, BUF1, cs1, cs2, N);
        }
        statfinal_kernel<<<1, F, 0, stream>>>(cs1, cs2, L[li].ga, meanv, istdv, N, F);

        long fb = (total + 255) / 256; if (fb > 4096) fb = 4096;
        normgelu_kernel<<<(int)fb, 256, 0, stream>>>(BUF1, meanv, istdv,
                                                     L[li].gw, L[li].gb, L[li].ga,
                                                     resb[li], BUF1, lf, total);
        cur = BUF1;
    }

    // pooling + head
    initpool_kernel<<<1, 64, 0, stream>>>(psum, pmax);
    colpool_kernel<<<(N + 127) / 128, 256, 0, stream>>>(cur, psum, pmax, N, 128);
    head_kernel<<<1, 64, 0, stream>>>(psum, pmax, wc1, bc1, lnw, lnb, wc2, bc2,
                                      (float*)d_out, N);
}